// Round 1
// baseline (528.427 us; speedup 1.0000x reference)
//
#include <hip/hip_runtime.h>
#include <hip/hip_bf16.h>
#include <cstdint>
#include <cstddef>

#define NNODES 50000
#define NEDGES 1600000
#define DIN 256
#define DH1 128
#define DH2 64

#define SCAN_CHUNK 2048
#define SCAN_NBLK 25  // ceil(50000/2048)

// ---------------- degree histogram (in-degree at dst) ----------------
__global__ void k_hist(const int* __restrict__ dst, int* __restrict__ cnt) {
    int stride = gridDim.x * blockDim.x;
    for (int e = blockIdx.x * blockDim.x + threadIdx.x; e < NEDGES; e += stride) {
        atomicAdd(&cnt[dst[e]], 1);
    }
}

// dinv[i] = rsqrt(deg_i), deg includes the self-loop (+1)
__global__ void k_dinv(const int* __restrict__ cnt, float* __restrict__ dinv) {
    int i = blockIdx.x * blockDim.x + threadIdx.x;
    if (i < NNODES) dinv[i] = rsqrtf((float)(cnt[i] + 1));
}

// ---------------- exclusive scan of cnt -> off (3-kernel) ----------------
__global__ void k_scan_partial(const int* __restrict__ cnt, int* __restrict__ bsum) {
    __shared__ int lds[256];
    int b = blockIdx.x, t = threadIdx.x;
    int base = b * SCAN_CHUNK + t * 8;
    int s = 0;
#pragma unroll
    for (int j = 0; j < 8; ++j) {
        int idx = base + j;
        if (idx < NNODES) s += cnt[idx];
    }
    lds[t] = s;
    __syncthreads();
    for (int d = 128; d > 0; d >>= 1) {
        if (t < d) lds[t] += lds[t + d];
        __syncthreads();
    }
    if (t == 0) bsum[b] = lds[0];
}

__global__ void k_scan_small(const int* __restrict__ bsum, int* __restrict__ bofs) {
    if (threadIdx.x == 0) {
        int run = 0;
        for (int i = 0; i < SCAN_NBLK; ++i) { bofs[i] = run; run += bsum[i]; }
    }
}

__global__ void k_scan_final(const int* __restrict__ cnt, const int* __restrict__ bofs,
                             int* __restrict__ off, int* __restrict__ cur) {
    __shared__ int lds[256];
    int b = blockIdx.x, t = threadIdx.x;
    int base = b * SCAN_CHUNK + t * 8;
    int v[8];
    int s = 0;
#pragma unroll
    for (int j = 0; j < 8; ++j) {
        int idx = base + j;
        v[j] = (idx < NNODES) ? cnt[idx] : 0;
        s += v[j];
    }
    lds[t] = s;
    __syncthreads();
    // inclusive Hillis-Steele scan over thread sums
    for (int d = 1; d < 256; d <<= 1) {
        int add = (t >= d) ? lds[t - d] : 0;
        __syncthreads();
        lds[t] += add;
        __syncthreads();
    }
    int run = bofs[b] + lds[t] - s;  // exclusive offset for this thread's 8 elems
#pragma unroll
    for (int j = 0; j < 8; ++j) {
        int idx = base + j;
        if (idx < NNODES) { off[idx] = run; cur[idx] = run; }
        run += v[j];
    }
}

// ---------------- CSR bucket scatter ----------------
__global__ void k_scatter(const int* __restrict__ src, const int* __restrict__ dst,
                          int* __restrict__ cur, int* __restrict__ csr) {
    int stride = gridDim.x * blockDim.x;
    for (int e = blockIdx.x * blockDim.x + threadIdx.x; e < NEDGES; e += stride) {
        int d = dst[e];
        int pos = atomicAdd(&cur[d], 1);
        csr[pos] = src[e];
    }
}

// ---------------- fp32 tiled GEMM with dinv row-scale epilogue ----------------
// Z[m][n] = (X[m,:] @ W[:,n]) * dinv[m]    (no bias here; bias applied post-agg)
template <int K, int NN>
__global__ __launch_bounds__(256) void k_gemm_scale(const float* __restrict__ X,
                                                    const float* __restrict__ W,
                                                    const float* __restrict__ dinv,
                                                    float* __restrict__ Z) {
    constexpr int BM = 64, BN = 64, BK = 16;
    __shared__ float As[BK][BM + 4];  // [k][m], +4 pad keeps float4 align & breaks conflicts
    __shared__ float Bs[BK][BN + 4];  // [k][n]
    int bm = blockIdx.x * BM;
    int bn = blockIdx.y * BN;
    int t = threadIdx.x;
    int tx = t & 15, ty = t >> 4;
    float acc[4][4] = {};
    for (int k0 = 0; k0 < K; k0 += BK) {
        {   // A tile: 64 rows x 16 k, one float4 per thread
            int row = t >> 2;
            int q = (t & 3) * 4;
            float4 a = make_float4(0.f, 0.f, 0.f, 0.f);
            int gr = bm + row;
            if (gr < NNODES)
                a = *reinterpret_cast<const float4*>(X + (size_t)gr * K + k0 + q);
            As[q + 0][row] = a.x;
            As[q + 1][row] = a.y;
            As[q + 2][row] = a.z;
            As[q + 3][row] = a.w;
        }
        {   // B tile: 16 k x 64 n, one float4 per thread
            int kr = t >> 4;
            int nc = (t & 15) * 4;
            float4 b = *reinterpret_cast<const float4*>(W + (size_t)(k0 + kr) * NN + bn + nc);
            *reinterpret_cast<float4*>(&Bs[kr][nc]) = b;
        }
        __syncthreads();
#pragma unroll
        for (int k = 0; k < BK; ++k) {
            float4 av = *reinterpret_cast<const float4*>(&As[k][ty * 4]);
            float4 bv = *reinterpret_cast<const float4*>(&Bs[k][tx * 4]);
            float a[4] = {av.x, av.y, av.z, av.w};
            float b[4] = {bv.x, bv.y, bv.z, bv.w};
#pragma unroll
            for (int i = 0; i < 4; ++i)
#pragma unroll
                for (int j = 0; j < 4; ++j) acc[i][j] = fmaf(a[i], b[j], acc[i][j]);
        }
        __syncthreads();
    }
#pragma unroll
    for (int i = 0; i < 4; ++i) {
        int m = bm + ty * 4 + i;
        if (m >= NNODES) continue;
        float di = dinv[m];
        float4 o = make_float4(acc[i][0] * di, acc[i][1] * di, acc[i][2] * di, acc[i][3] * di);
        *reinterpret_cast<float4*>(Z + (size_t)m * NN + bn + tx * 4) = o;
    }
}

// ---------------- aggregation: one wave per node ----------------
// out[i] = relu( dinv[i] * ( zs[i] + sum_{src in N(i)} zs[src] ) + bias )
template <int D>
__global__ __launch_bounds__(256) void k_agg(const float* __restrict__ zs,
                                             const int* __restrict__ csr,
                                             const int* __restrict__ off,
                                             const int* __restrict__ cnt,
                                             const float* __restrict__ dinv,
                                             const float* __restrict__ bias,
                                             float* __restrict__ out) {
    constexpr int F = D / 64;  // floats per lane (2 for D=128, 1 for D=64)
    int wid = (blockIdx.x * 256 + threadIdx.x) >> 6;
    int lane = threadIdx.x & 63;
    if (wid >= NNODES) return;
    int start = off[wid];
    int c = cnt[wid];
    float di = dinv[wid];
    float acc[F];
    {
        const float* zp = zs + (size_t)wid * D + lane * F;  // self-loop term
#pragma unroll
        for (int f = 0; f < F; ++f) acc[f] = zp[f];
    }
#pragma unroll 4
    for (int j = 0; j < c; ++j) {
        int s = csr[start + j];  // wave-uniform broadcast load
        const float* zp = zs + (size_t)s * D + lane * F;
#pragma unroll
        for (int f = 0; f < F; ++f) acc[f] += zp[f];
    }
#pragma unroll
    for (int f = 0; f < F; ++f) {
        float v = fmaf(acc[f], di, bias[lane * F + f]);
        out[(size_t)wid * D + lane * F + f] = fmaxf(v, 0.0f);
    }
}

// ---------------- launcher ----------------
extern "C" void kernel_launch(void* const* d_in, const int* in_sizes, int n_in,
                              void* d_out, int out_size, void* d_ws, size_t ws_size,
                              hipStream_t stream) {
    const float* x = (const float*)d_in[0];
    const int* ei = (const int*)d_in[1];  // [2, E] int32 per harness convention
    const float* W1 = (const float*)d_in[2];
    const float* b1 = (const float*)d_in[3];
    const float* W2 = (const float*)d_in[4];
    const float* b2 = (const float*)d_in[5];
    float* out = (float*)d_out;

    char* ws = (char*)d_ws;
    int* cnt = (int*)(ws + 0);              // N ints
    int* off = (int*)(ws + 200192);         // N ints
    int* cur = (int*)(ws + 400384);         // N ints
    float* dinv = (float*)(ws + 600576);    // N floats
    int* bsum = (int*)(ws + 800768);        // 25 ints
    int* bofs = (int*)(ws + 800896);        // 25 ints
    int* csr = (int*)(ws + 801024);         // E ints = 6.4 MB
    float* zs1 = (float*)(ws + 7201024);    // N*128 floats = 25.6 MB
    float* h1 = (float*)(ws + 32801024);    // N*128 floats = 25.6 MB
    float* zs2 = zs1;                       // alias: zs1 dead after agg1
    // total ws use: ~58.4 MB

    const int* esrc = ei;
    const int* edst = ei + NEDGES;

    hipMemsetAsync(cnt, 0, NNODES * sizeof(int), stream);
    k_hist<<<1024, 256, 0, stream>>>(edst, cnt);
    k_dinv<<<(NNODES + 255) / 256, 256, 0, stream>>>(cnt, dinv);
    k_scan_partial<<<SCAN_NBLK, 256, 0, stream>>>(cnt, bsum);
    k_scan_small<<<1, 64, 0, stream>>>(bsum, bofs);
    k_scan_final<<<SCAN_NBLK, 256, 0, stream>>>(cnt, bofs, off, cur);
    k_scatter<<<1024, 256, 0, stream>>>(esrc, edst, cur, csr);

    dim3 g1((NNODES + 63) / 64, DH1 / 64);
    k_gemm_scale<DIN, DH1><<<g1, 256, 0, stream>>>(x, W1, dinv, zs1);
    k_agg<DH1><<<NNODES / 4, 256, 0, stream>>>(zs1, csr, off, cnt, dinv, b1, h1);

    dim3 g2((NNODES + 63) / 64, DH2 / 64);
    k_gemm_scale<DH1, DH2><<<g2, 256, 0, stream>>>(h1, W2, dinv, zs2);
    k_agg<DH2><<<NNODES / 4, 256, 0, stream>>>(zs2, csr, off, cnt, dinv, b2, out);
}

// Round 2
// 419.888 us; speedup vs baseline: 1.2585x; 1.2585x over previous
//
#include <hip/hip_runtime.h>
#include <hip/hip_bf16.h>
#include <cstdint>
#include <cstddef>

#define NNODES 50000
#define NEDGES 1600000
#define DIN 256
#define DH1 128
#define DH2 64

#define NBKT 196        // ceil(50000/256) buckets of 256 dst nodes
#define NCHUNK 128
#define CHUNKE 12500    // 128*12500 = 1.6M exactly
#define STAGE_CAP 10240 // bucket edges ~Poisson(8163); cap with big margin

// ---------- 1. per-chunk bucket histogram ----------
__global__ __launch_bounds__(256) void k_chunkhist(const int* __restrict__ dst,
                                                   int* __restrict__ counts) {
    __shared__ int hist[NBKT];
    int c = blockIdx.x, t = threadIdx.x;
    if (t < NBKT) hist[t] = 0;
    __syncthreads();
    int e0 = c * CHUNKE, e1 = min(NEDGES, e0 + CHUNKE);
    for (int e = e0 + t; e < e1; e += 256) atomicAdd(&hist[dst[e] >> 8], 1);
    __syncthreads();
    if (t < NBKT) counts[c * NBKT + t] = hist[t];
}

// ---------- 2. scan: counts[c][b] -> global offsets; bucket ranges ----------
__global__ __launch_bounds__(256) void k_bktscan(int* __restrict__ counts,
                                                 int* __restrict__ bktstart,
                                                 int* __restrict__ bktcnt) {
    __shared__ int lds[256];
    int t = threadIdx.x;
    int total = 0;
    if (t < NBKT)
        for (int c = 0; c < NCHUNK; ++c) total += counts[c * NBKT + t];
    lds[t] = total;
    __syncthreads();
    for (int d = 1; d < 256; d <<= 1) {
        int add = (t >= d) ? lds[t - d] : 0;
        __syncthreads();
        lds[t] += add;
        __syncthreads();
    }
    int base = lds[t] - total;  // exclusive bucket base
    if (t < NBKT) {
        bktstart[t] = base;
        bktcnt[t] = total;
        int run = base;
        for (int c = 0; c < NCHUNK; ++c) {
            int x = counts[c * NBKT + t];
            counts[c * NBKT + t] = run;  // in-place: now per-(chunk,bucket) offset
            run += x;
        }
    }
}

// ---------- 3. coarse scatter into bucket-sorted pairs ----------
__global__ __launch_bounds__(256) void k_pairscatter(const int* __restrict__ src,
                                                     const int* __restrict__ dst,
                                                     const int* __restrict__ counts,
                                                     uint32_t* __restrict__ pairs) {
    __shared__ int cur[NBKT];
    int c = blockIdx.x, t = threadIdx.x;
    if (t < NBKT) cur[t] = counts[c * NBKT + t];
    __syncthreads();
    int e0 = c * CHUNKE, e1 = min(NEDGES, e0 + CHUNKE);
    for (int e = e0 + t; e < e1; e += 256) {
        int d = dst[e];
        int pos = atomicAdd(&cur[d >> 8], 1);
        pairs[pos] = ((uint32_t)(d & 255) << 16) | (uint32_t)src[e];
    }
}

// ---------- 4. fine sort per bucket (LDS) -> csr, off, dinv ----------
__global__ __launch_bounds__(256) void k_sortbucket(const uint32_t* __restrict__ pairs,
                                                    const int* __restrict__ bktstart,
                                                    const int* __restrict__ bktcnt,
                                                    int* __restrict__ csr,
                                                    int* __restrict__ off,
                                                    float* __restrict__ dinv) {
    __shared__ int hist[256];
    __shared__ int cur[256];
    __shared__ int stage[STAGE_CAP];
    int b = blockIdx.x, t = threadIdx.x;
    int e0 = bktstart[b], ecnt = bktcnt[b];
    hist[t] = 0;
    __syncthreads();
    for (int e = e0 + t; e < e0 + ecnt; e += 256)
        atomicAdd(&hist[pairs[e] >> 16], 1);
    __syncthreads();
    int v = hist[t];
    cur[t] = v;
    __syncthreads();
    for (int d = 1; d < 256; d <<= 1) {
        int add = (t >= d) ? cur[t - d] : 0;
        __syncthreads();
        cur[t] += add;
        __syncthreads();
    }
    int excl = cur[t] - v;  // within-bucket exclusive offset for node (b<<8)+t
    int node = (b << 8) + t;
    if (node < NNODES) {
        off[node] = e0 + excl;
        dinv[node] = rsqrtf((float)(v + 1));  // +1 self-loop
    }
    if (b == NBKT - 1 && t == 0) off[NNODES] = NEDGES;
    __syncthreads();
    cur[t] = e0 + excl;  // global cursor
    __syncthreads();
    if (ecnt <= STAGE_CAP) {
        for (int e = e0 + t; e < e0 + ecnt; e += 256) {
            uint32_t p = pairs[e];
            int pos = atomicAdd(&cur[p >> 16], 1);
            stage[pos - e0] = (int)(p & 0xFFFF);
        }
        __syncthreads();
        for (int i = t; i < ecnt; i += 256) csr[e0 + i] = stage[i];  // coalesced
    } else {  // overflow fallback (shouldn't trigger for this input)
        for (int e = e0 + t; e < e0 + ecnt; e += 256) {
            uint32_t p = pairs[e];
            int pos = atomicAdd(&cur[p >> 16], 1);
            csr[pos] = (int)(p & 0xFFFF);
        }
    }
}

// ---------- fp32 tiled GEMM with dinv row-scale epilogue ----------
template <int K, int NN>
__global__ __launch_bounds__(256) void k_gemm_scale(const float* __restrict__ X,
                                                    const float* __restrict__ W,
                                                    const float* __restrict__ dinv,
                                                    float* __restrict__ Z) {
    constexpr int BM = 64, BN = 64, BK = 16;
    __shared__ float As[BK][BM + 4];
    __shared__ float Bs[BK][BN + 4];
    int bm = blockIdx.x * BM;
    int bn = blockIdx.y * BN;
    int t = threadIdx.x;
    int tx = t & 15, ty = t >> 4;
    float acc[4][4] = {};
    for (int k0 = 0; k0 < K; k0 += BK) {
        {
            int row = t >> 2;
            int q = (t & 3) * 4;
            float4 a = make_float4(0.f, 0.f, 0.f, 0.f);
            int gr = bm + row;
            if (gr < NNODES)
                a = *reinterpret_cast<const float4*>(X + (size_t)gr * K + k0 + q);
            As[q + 0][row] = a.x;
            As[q + 1][row] = a.y;
            As[q + 2][row] = a.z;
            As[q + 3][row] = a.w;
        }
        {
            int kr = t >> 4;
            int nc = (t & 15) * 4;
            float4 bv = *reinterpret_cast<const float4*>(W + (size_t)(k0 + kr) * NN + bn + nc);
            *reinterpret_cast<float4*>(&Bs[kr][nc]) = bv;
        }
        __syncthreads();
#pragma unroll
        for (int k = 0; k < BK; ++k) {
            float4 av = *reinterpret_cast<const float4*>(&As[k][ty * 4]);
            float4 bv = *reinterpret_cast<const float4*>(&Bs[k][tx * 4]);
            float a[4] = {av.x, av.y, av.z, av.w};
            float bb[4] = {bv.x, bv.y, bv.z, bv.w};
#pragma unroll
            for (int i = 0; i < 4; ++i)
#pragma unroll
                for (int j = 0; j < 4; ++j) acc[i][j] = fmaf(a[i], bb[j], acc[i][j]);
        }
        __syncthreads();
    }
#pragma unroll
    for (int i = 0; i < 4; ++i) {
        int m = bm + ty * 4 + i;
        if (m >= NNODES) continue;
        float di = dinv[m];
        float4 o = make_float4(acc[i][0] * di, acc[i][1] * di, acc[i][2] * di, acc[i][3] * di);
        *reinterpret_cast<float4*>(Z + (size_t)m * NN + bn + tx * 4) = o;
    }
}

// ---------- aggregation: one wave per node, register accumulate ----------
// out[i] = relu( dinv[i] * ( zs[i] + sum_{src in N(i)} zs[src] ) + bias )
template <int D>
__global__ __launch_bounds__(256) void k_agg(const float* __restrict__ zs,
                                             const int* __restrict__ csr,
                                             const int* __restrict__ off,
                                             const float* __restrict__ dinv,
                                             const float* __restrict__ bias,
                                             float* __restrict__ out) {
    int wid = (blockIdx.x * 256 + threadIdx.x) >> 6;
    int lane = threadIdx.x & 63;
    if (wid >= NNODES) return;
    int start = off[wid];
    int c = off[wid + 1] - start;
    float di = dinv[wid];
    if constexpr (D == 128) {
        float2 acc0 = *reinterpret_cast<const float2*>(zs + (size_t)wid * D + lane * 2);
        float2 acc1 = make_float2(0.f, 0.f);
        int j = 0;
        for (; j + 1 < c; j += 2) {
            int s0 = csr[start + j];
            int s1 = csr[start + j + 1];
            float2 a = *reinterpret_cast<const float2*>(zs + (size_t)s0 * D + lane * 2);
            float2 bb = *reinterpret_cast<const float2*>(zs + (size_t)s1 * D + lane * 2);
            acc0.x += a.x; acc0.y += a.y;
            acc1.x += bb.x; acc1.y += bb.y;
        }
        if (j < c) {
            int s0 = csr[start + j];
            float2 a = *reinterpret_cast<const float2*>(zs + (size_t)s0 * D + lane * 2);
            acc0.x += a.x; acc0.y += a.y;
        }
        float2 bv = *reinterpret_cast<const float2*>(bias + lane * 2);
        float2 o;
        o.x = fmaxf(fmaf(acc0.x + acc1.x, di, bv.x), 0.f);
        o.y = fmaxf(fmaf(acc0.y + acc1.y, di, bv.y), 0.f);
        *reinterpret_cast<float2*>(out + (size_t)wid * D + lane * 2) = o;
    } else {
        float acc0 = zs[(size_t)wid * D + lane];
        float acc1 = 0.f;
        int j = 0;
        for (; j + 1 < c; j += 2) {
            int s0 = csr[start + j];
            int s1 = csr[start + j + 1];
            acc0 += zs[(size_t)s0 * D + lane];
            acc1 += zs[(size_t)s1 * D + lane];
        }
        if (j < c) acc0 += zs[(size_t)csr[start + j] * D + lane];
        float o = fmaxf(fmaf(acc0 + acc1, di, bias[lane]), 0.f);
        out[(size_t)wid * D + lane] = o;
    }
}

// ---------------- launcher ----------------
extern "C" void kernel_launch(void* const* d_in, const int* in_sizes, int n_in,
                              void* d_out, int out_size, void* d_ws, size_t ws_size,
                              hipStream_t stream) {
    const float* x = (const float*)d_in[0];
    const int* ei = (const int*)d_in[1];  // [2, E] int32
    const float* W1 = (const float*)d_in[2];
    const float* b1 = (const float*)d_in[3];
    const float* W2 = (const float*)d_in[4];
    const float* b2 = (const float*)d_in[5];
    float* out = (float*)d_out;

    char* ws = (char*)d_ws;
    int* counts = (int*)(ws + 0);             // NCHUNK*NBKT = 100,352 B
    int* bktstart = (int*)(ws + 101376);      // 784 B
    int* bktcnt = (int*)(ws + 102400);        // 784 B
    int* off = (int*)(ws + 103424);           // (N+1)*4 = 200,004 B
    float* dinv = (float*)(ws + 303616);      // 200,000 B
    int* csr = (int*)(ws + 503808);           // 6,400,000 B
    float* zs1 = (float*)(ws + 6904832);      // 25,600,000 B
    float* h1 = (float*)(ws + 32504832);      // 25,600,000 B (ends ~58.1 MB)
    uint32_t* pairs = (uint32_t*)h1;          // alias: pairs dead before h1 live
    float* zs2 = zs1;                         // alias: zs1 dead after agg1

    const int* esrc = ei;
    const int* edst = ei + NEDGES;

    k_chunkhist<<<NCHUNK, 256, 0, stream>>>(edst, counts);
    k_bktscan<<<1, 256, 0, stream>>>(counts, bktstart, bktcnt);
    k_pairscatter<<<NCHUNK, 256, 0, stream>>>(esrc, edst, counts, pairs);
    k_sortbucket<<<NBKT, 256, 0, stream>>>(pairs, bktstart, bktcnt, csr, off, dinv);

    dim3 g1((NNODES + 63) / 64, DH1 / 64);
    k_gemm_scale<DIN, DH1><<<g1, 256, 0, stream>>>(x, W1, dinv, zs1);
    k_agg<DH1><<<NNODES / 4, 256, 0, stream>>>(zs1, csr, off, dinv, b1, h1);

    dim3 g2((NNODES + 63) / 64, DH2 / 64);
    k_gemm_scale<DH1, DH2><<<g2, 256, 0, stream>>>(h1, W2, dinv, zs2);
    k_agg<DH2><<<NNODES / 4, 256, 0, stream>>>(zs2, csr, off, dinv, b2, out);
}

// Round 6
// 349.874 us; speedup vs baseline: 1.5103x; 1.2001x over previous
//
#include <hip/hip_runtime.h>
#include <hip/hip_bf16.h>
#include <cstdint>
#include <cstddef>

#define NNODES 50000
#define NEDGES 1600000
#define DIN 256
#define DH1 128
#define DH2 64

#define NBKT 196        // ceil(50000/256) buckets of 256 dst nodes
#define NCHUNK 128
#define CHUNKE 12500    // 128*12500 = 1.6M exactly
#define STAGE_CAP 10240 // bucket edges ~Poisson(8163); cap with big margin

__device__ __forceinline__ float bflo(uint32_t u) { return __uint_as_float(u << 16); }
__device__ __forceinline__ float bfhi(uint32_t u) { return __uint_as_float(u & 0xffff0000u); }
__device__ __forceinline__ uint16_t f2bf(float f) {
    uint32_t u = __float_as_uint(f);
    u += 0x7fffu + ((u >> 16) & 1u);  // round-to-nearest-even
    return (uint16_t)(u >> 16);
}

// ---------- 1. per-chunk bucket histogram ----------
__global__ __launch_bounds__(256) void k_chunkhist(const int* __restrict__ dst,
                                                   int* __restrict__ counts) {
    __shared__ int hist[NBKT];
    int c = blockIdx.x, t = threadIdx.x;
    if (t < NBKT) hist[t] = 0;
    __syncthreads();
    int e0 = c * CHUNKE, e1 = min(NEDGES, e0 + CHUNKE);
    for (int e = e0 + t; e < e1; e += 256) atomicAdd(&hist[dst[e] >> 8], 1);
    __syncthreads();
    if (t < NBKT) counts[c * NBKT + t] = hist[t];
}

// ---------- 2. scan: counts[c][b] -> global offsets; bucket ranges ----------
__global__ __launch_bounds__(256) void k_bktscan(int* __restrict__ counts,
                                                 int* __restrict__ bktstart,
                                                 int* __restrict__ bktcnt) {
    __shared__ int lds[256];
    int t = threadIdx.x;
    int total = 0;
    if (t < NBKT)
        for (int c = 0; c < NCHUNK; ++c) total += counts[c * NBKT + t];
    lds[t] = total;
    __syncthreads();
    for (int d = 1; d < 256; d <<= 1) {
        int add = (t >= d) ? lds[t - d] : 0;
        __syncthreads();
        lds[t] += add;
        __syncthreads();
    }
    int base = lds[t] - total;  // exclusive bucket base
    if (t < NBKT) {
        bktstart[t] = base;
        bktcnt[t] = total;
        int run = base;
        for (int c = 0; c < NCHUNK; ++c) {
            int x = counts[c * NBKT + t];
            counts[c * NBKT + t] = run;  // in-place: now per-(chunk,bucket) offset
            run += x;
        }
    }
}

// ---------- 3. coarse scatter into bucket-sorted pairs ----------
__global__ __launch_bounds__(256) void k_pairscatter(const int* __restrict__ src,
                                                     const int* __restrict__ dst,
                                                     const int* __restrict__ counts,
                                                     uint32_t* __restrict__ pairs) {
    __shared__ int cur[NBKT];
    int c = blockIdx.x, t = threadIdx.x;
    if (t < NBKT) cur[t] = counts[c * NBKT + t];
    __syncthreads();
    int e0 = c * CHUNKE, e1 = min(NEDGES, e0 + CHUNKE);
    for (int e = e0 + t; e < e1; e += 256) {
        int d = dst[e];
        int pos = atomicAdd(&cur[d >> 8], 1);
        pairs[pos] = ((uint32_t)(d & 255) << 16) | (uint32_t)src[e];
    }
}

// ---------- 4. fine sort per bucket (LDS) -> csr, off, dinv ----------
__global__ __launch_bounds__(256) void k_sortbucket(const uint32_t* __restrict__ pairs,
                                                    const int* __restrict__ bktstart,
                                                    const int* __restrict__ bktcnt,
                                                    int* __restrict__ csr,
                                                    int* __restrict__ off,
                                                    float* __restrict__ dinv) {
    __shared__ int hist[256];
    __shared__ int cur[256];
    __shared__ int stage[STAGE_CAP];
    int b = blockIdx.x, t = threadIdx.x;
    int e0 = bktstart[b], ecnt = bktcnt[b];
    hist[t] = 0;
    __syncthreads();
    for (int e = e0 + t; e < e0 + ecnt; e += 256)
        atomicAdd(&hist[pairs[e] >> 16], 1);
    __syncthreads();
    int v = hist[t];
    cur[t] = v;
    __syncthreads();
    for (int d = 1; d < 256; d <<= 1) {
        int add = (t >= d) ? cur[t - d] : 0;
        __syncthreads();
        cur[t] += add;
        __syncthreads();
    }
    int excl = cur[t] - v;  // within-bucket exclusive offset for node (b<<8)+t
    int node = (b << 8) + t;
    if (node < NNODES) {
        off[node] = e0 + excl;
        dinv[node] = rsqrtf((float)(v + 1));  // +1 self-loop
    }
    if (b == NBKT - 1 && t == 0) off[NNODES] = NEDGES;
    __syncthreads();
    cur[t] = e0 + excl;  // global cursor
    __syncthreads();
    if (ecnt <= STAGE_CAP) {
        for (int e = e0 + t; e < e0 + ecnt; e += 256) {
            uint32_t p = pairs[e];
            int pos = atomicAdd(&cur[p >> 16], 1);
            stage[pos - e0] = (int)(p & 0xFFFF);
        }
        __syncthreads();
        for (int i = t; i < ecnt; i += 256) csr[e0 + i] = stage[i];  // coalesced
    } else {  // overflow fallback
        for (int e = e0 + t; e < e0 + ecnt; e += 256) {
            uint32_t p = pairs[e];
            int pos = atomicAdd(&cur[p >> 16], 1);
            csr[pos] = (int)(p & 0xFFFF);
        }
    }
}

// ---------- fp32 tiled GEMM, epilogue: row-scale by dinv + pack bf16 ----------
// Zbf[m][n] = bf16( (X[m,:] @ W[:,n]) * dinv[m] )
template <int K, int NN>
__global__ __launch_bounds__(256) void k_gemm_scale(const float* __restrict__ X,
                                                    const float* __restrict__ W,
                                                    const float* __restrict__ dinv,
                                                    uint16_t* __restrict__ Z) {
    constexpr int BM = 64, BN = 64, BK = 16;
    __shared__ float As[BK][BM + 4];
    __shared__ float Bs[BK][BN + 4];
    int bm = blockIdx.x * BM;
    int bn = blockIdx.y * BN;
    int t = threadIdx.x;
    int tx = t & 15, ty = t >> 4;
    float acc[4][4] = {};
    for (int k0 = 0; k0 < K; k0 += BK) {
        {
            int row = t >> 2;
            int q = (t & 3) * 4;
            float4 a = make_float4(0.f, 0.f, 0.f, 0.f);
            int gr = bm + row;
            if (gr < NNODES)
                a = *reinterpret_cast<const float4*>(X + (size_t)gr * K + k0 + q);
            As[q + 0][row] = a.x;
            As[q + 1][row] = a.y;
            As[q + 2][row] = a.z;
            As[q + 3][row] = a.w;
        }
        {
            int kr = t >> 4;
            int nc = (t & 15) * 4;
            float4 bv = *reinterpret_cast<const float4*>(W + (size_t)(k0 + kr) * NN + bn + nc);
            *reinterpret_cast<float4*>(&Bs[kr][nc]) = bv;
        }
        __syncthreads();
#pragma unroll
        for (int k = 0; k < BK; ++k) {
            float4 av = *reinterpret_cast<const float4*>(&As[k][ty * 4]);
            float4 bv = *reinterpret_cast<const float4*>(&Bs[k][tx * 4]);
            float a[4] = {av.x, av.y, av.z, av.w};
            float bb[4] = {bv.x, bv.y, bv.z, bv.w};
#pragma unroll
            for (int i = 0; i < 4; ++i)
#pragma unroll
                for (int j = 0; j < 4; ++j) acc[i][j] = fmaf(a[i], bb[j], acc[i][j]);
        }
        __syncthreads();
    }
#pragma unroll
    for (int i = 0; i < 4; ++i) {
        int m = bm + ty * 4 + i;
        if (m >= NNODES) continue;
        float di = dinv[m];
        uint32_t p0 = (uint32_t)f2bf(acc[i][0] * di) | ((uint32_t)f2bf(acc[i][1] * di) << 16);
        uint32_t p1 = (uint32_t)f2bf(acc[i][2] * di) | ((uint32_t)f2bf(acc[i][3] * di) << 16);
        *reinterpret_cast<uint2*>(Z + (size_t)m * NN + bn + tx * 4) = make_uint2(p0, p1);
    }
}

// ---------- aggregation: one wave per node, bf16 gather, fp32 accumulate ----------
// out[i] = relu( dinv[i] * ( zs[i] + sum_{src in N(i)} zs[src] ) + bias )
template <int D>
__global__ __launch_bounds__(256) void k_agg_bf(const uint16_t* __restrict__ zs,
                                                const int* __restrict__ csr,
                                                const int* __restrict__ off,
                                                const float* __restrict__ dinv,
                                                const float* __restrict__ bias,
                                                float* __restrict__ out) {
    int wid = (blockIdx.x * 256 + threadIdx.x) >> 6;
    int lane = threadIdx.x & 63;
    if (wid >= NNODES) return;
    int start = off[wid];
    int c = off[wid + 1] - start;
    float di = dinv[wid];
    if constexpr (D == 128) {
        const uint32_t* Z = reinterpret_cast<const uint32_t*>(zs);  // 2 bf16 per u32
        uint32_t us = Z[(size_t)wid * 64 + lane];
        float ax = bflo(us), ay = bfhi(us);
        float bx = 0, by = 0, cx = 0, cy = 0, dx = 0, dy = 0;
        int j = 0;
        for (; j + 3 < c; j += 4) {
            int s0 = csr[start + j], s1 = csr[start + j + 1];
            int s2 = csr[start + j + 2], s3 = csr[start + j + 3];
            uint32_t u0 = Z[(size_t)s0 * 64 + lane];
            uint32_t u1 = Z[(size_t)s1 * 64 + lane];
            uint32_t u2 = Z[(size_t)s2 * 64 + lane];
            uint32_t u3 = Z[(size_t)s3 * 64 + lane];
            ax += bflo(u0); ay += bfhi(u0);
            bx += bflo(u1); by += bfhi(u1);
            cx += bflo(u2); cy += bfhi(u2);
            dx += bflo(u3); dy += bfhi(u3);
        }
        for (; j < c; ++j) {
            uint32_t u = Z[(size_t)csr[start + j] * 64 + lane];
            ax += bflo(u); ay += bfhi(u);
        }
        float sx = (ax + bx) + (cx + dx);
        float sy = (ay + by) + (cy + dy);
        float2 bv = *reinterpret_cast<const float2*>(bias + lane * 2);
        float2 o;
        o.x = fmaxf(fmaf(sx, di, bv.x), 0.f);
        o.y = fmaxf(fmaf(sy, di, bv.y), 0.f);
        *reinterpret_cast<float2*>(out + (size_t)wid * 128 + lane * 2) = o;
    } else {  // D == 64, one bf16 per lane
        float a = __uint_as_float(((uint32_t)zs[(size_t)wid * 64 + lane]) << 16);
        float b = 0, cc = 0, d = 0;
        int j = 0;
        for (; j + 3 < c; j += 4) {
            int s0 = csr[start + j], s1 = csr[start + j + 1];
            int s2 = csr[start + j + 2], s3 = csr[start + j + 3];
            a += __uint_as_float(((uint32_t)zs[(size_t)s0 * 64 + lane]) << 16);
            b += __uint_as_float(((uint32_t)zs[(size_t)s1 * 64 + lane]) << 16);
            cc += __uint_as_float(((uint32_t)zs[(size_t)s2 * 64 + lane]) << 16);
            d += __uint_as_float(((uint32_t)zs[(size_t)s3 * 64 + lane]) << 16);
        }
        for (; j < c; ++j)
            a += __uint_as_float(((uint32_t)zs[(size_t)csr[start + j] * 64 + lane]) << 16);
        float s = (a + b) + (cc + d);
        float o = fmaxf(fmaf(s, di, bias[lane]), 0.f);
        out[(size_t)wid * 64 + lane] = o;
    }
}

// ---------------- launcher ----------------
extern "C" void kernel_launch(void* const* d_in, const int* in_sizes, int n_in,
                              void* d_out, int out_size, void* d_ws, size_t ws_size,
                              hipStream_t stream) {
    const float* x = (const float*)d_in[0];
    const int* ei = (const int*)d_in[1];  // [2, E] int32
    const float* W1 = (const float*)d_in[2];
    const float* b1 = (const float*)d_in[3];
    const float* W2 = (const float*)d_in[4];
    const float* b2 = (const float*)d_in[5];
    float* out = (float*)d_out;

    char* ws = (char*)d_ws;
    int* counts = (int*)(ws + 0);             // NCHUNK*NBKT ints = 100,352 B
    int* bktstart = (int*)(ws + 101376);
    int* bktcnt = (int*)(ws + 102400);
    int* off = (int*)(ws + 103424);           // (N+1)*4
    float* dinv = (float*)(ws + 303616);      // N*4
    int* csr = (int*)(ws + 503808);           // E*4 = 6.4 MB -> ends 6,903,808
    uint16_t* zs1 = (uint16_t*)(ws + 6904832);   // N*128 bf16 = 12.8 MB -> ends 19,704,832
    float* h1 = (float*)(ws + 19705856);         // N*128 fp32 = 25.6 MB -> ends 45,305,856
    uint32_t* pairs = (uint32_t*)h1;             // alias: pairs dead before h1 live
    uint16_t* zs2 = zs1;                         // alias: zs1 dead after agg1

    const int* esrc = ei;
    const int* edst = ei + NEDGES;

    k_chunkhist<<<NCHUNK, 256, 0, stream>>>(edst, counts);
    k_bktscan<<<1, 256, 0, stream>>>(counts, bktstart, bktcnt);
    k_pairscatter<<<NCHUNK, 256, 0, stream>>>(esrc, edst, counts, pairs);
    k_sortbucket<<<NBKT, 256, 0, stream>>>(pairs, bktstart, bktcnt, csr, off, dinv);

    dim3 g1((NNODES + 63) / 64, DH1 / 64);
    k_gemm_scale<DIN, DH1><<<g1, 256, 0, stream>>>(x, W1, dinv, zs1);
    k_agg_bf<DH1><<<NNODES / 4, 256, 0, stream>>>(zs1, csr, off, dinv, b1, h1);

    dim3 g2((NNODES + 63) / 64, DH2 / 64);
    k_gemm_scale<DH1, DH2><<<g2, 256, 0, stream>>>(h1, W2, dinv, zs2);
    k_agg_bf<DH2><<<NNODES / 4, 256, 0, stream>>>(zs2, csr, off, dinv, b2, out);
}

// Round 9
// 316.843 us; speedup vs baseline: 1.6678x; 1.1043x over previous
//
#include <hip/hip_runtime.h>
#include <hip/hip_bf16.h>
#include <cstdint>
#include <cstddef>

#define NNODES 50000
#define NEDGES 1600000
#define DIN 256
#define DH1 128
#define DH2 64

#define NBKT 196        // ceil(50000/256) buckets of 256 dst nodes
#define NCHUNK 128
#define CHUNKE 12500    // 128*12500 = 1.6M exactly
#define STAGE_CAP 10240 // bucket edges ~Poisson(8163); cap with big margin

__device__ __forceinline__ float bflo(uint32_t u) { return __uint_as_float(u << 16); }
__device__ __forceinline__ float bfhi(uint32_t u) { return __uint_as_float(u & 0xffff0000u); }
__device__ __forceinline__ uint16_t f2bf(float f) {
    uint32_t u = __float_as_uint(f);
    u += 0x7fffu + ((u >> 16) & 1u);  // round-to-nearest-even
    return (uint16_t)(u >> 16);
}

using b8 = __attribute__((ext_vector_type(8))) short;   // 8 bf16 = 4 VGPRs (MFMA A/B frag)
using f4x = __attribute__((ext_vector_type(4))) float;  // MFMA C/D frag

// ---------- 1. per-chunk bucket histogram ----------
__global__ __launch_bounds__(256) void k_chunkhist(const int* __restrict__ dst,
                                                   int* __restrict__ counts) {
    __shared__ int hist[NBKT];
    int c = blockIdx.x, t = threadIdx.x;
    if (t < NBKT) hist[t] = 0;
    __syncthreads();
    int e0 = c * CHUNKE, e1 = min(NEDGES, e0 + CHUNKE);
    for (int e = e0 + t; e < e1; e += 256) atomicAdd(&hist[dst[e] >> 8], 1);
    __syncthreads();
    if (t < NBKT) counts[c * NBKT + t] = hist[t];
}

// ---------- 2. scan: counts[c][b] -> global offsets; bucket ranges ----------
__global__ __launch_bounds__(256) void k_bktscan(int* __restrict__ counts,
                                                 int* __restrict__ bktstart,
                                                 int* __restrict__ bktcnt) {
    __shared__ int lds[256];
    int t = threadIdx.x;
    int total = 0;
    if (t < NBKT)
        for (int c = 0; c < NCHUNK; ++c) total += counts[c * NBKT + t];
    lds[t] = total;
    __syncthreads();
    for (int d = 1; d < 256; d <<= 1) {
        int add = (t >= d) ? lds[t - d] : 0;
        __syncthreads();
        lds[t] += add;
        __syncthreads();
    }
    int base = lds[t] - total;  // exclusive bucket base
    if (t < NBKT) {
        bktstart[t] = base;
        bktcnt[t] = total;
        int run = base;
        for (int c = 0; c < NCHUNK; ++c) {
            int x = counts[c * NBKT + t];
            counts[c * NBKT + t] = run;  // in-place: now per-(chunk,bucket) offset
            run += x;
        }
    }
}

// ---------- 3. coarse scatter into bucket-sorted pairs ----------
__global__ __launch_bounds__(256) void k_pairscatter(const int* __restrict__ src,
                                                     const int* __restrict__ dst,
                                                     const int* __restrict__ counts,
                                                     uint32_t* __restrict__ pairs) {
    __shared__ int cur[NBKT];
    int c = blockIdx.x, t = threadIdx.x;
    if (t < NBKT) cur[t] = counts[c * NBKT + t];
    __syncthreads();
    int e0 = c * CHUNKE, e1 = min(NEDGES, e0 + CHUNKE);
    for (int e = e0 + t; e < e1; e += 256) {
        int d = dst[e];
        int pos = atomicAdd(&cur[d >> 8], 1);
        pairs[pos] = ((uint32_t)(d & 255) << 16) | (uint32_t)src[e];
    }
}

// ---------- 4. fine sort per bucket (LDS) -> csr, off, dinv ----------
__global__ __launch_bounds__(256) void k_sortbucket(const uint32_t* __restrict__ pairs,
                                                    const int* __restrict__ bktstart,
                                                    const int* __restrict__ bktcnt,
                                                    int* __restrict__ csr,
                                                    int* __restrict__ off,
                                                    float* __restrict__ dinv) {
    __shared__ int hist[256];
    __shared__ int cur[256];
    __shared__ int stage[STAGE_CAP];
    int b = blockIdx.x, t = threadIdx.x;
    int e0 = bktstart[b], ecnt = bktcnt[b];
    hist[t] = 0;
    __syncthreads();
    for (int e = e0 + t; e < e0 + ecnt; e += 256)
        atomicAdd(&hist[pairs[e] >> 16], 1);
    __syncthreads();
    int v = hist[t];
    cur[t] = v;
    __syncthreads();
    for (int d = 1; d < 256; d <<= 1) {
        int add = (t >= d) ? cur[t - d] : 0;
        __syncthreads();
        cur[t] += add;
        __syncthreads();
    }
    int excl = cur[t] - v;  // within-bucket exclusive offset for node (b<<8)+t
    int node = (b << 8) + t;
    if (node < NNODES) {
        off[node] = e0 + excl;
        dinv[node] = rsqrtf((float)(v + 1));  // +1 self-loop
    }
    if (b == NBKT - 1 && t == 0) off[NNODES] = NEDGES;
    __syncthreads();
    cur[t] = e0 + excl;  // global cursor
    __syncthreads();
    if (ecnt <= STAGE_CAP) {
        for (int e = e0 + t; e < e0 + ecnt; e += 256) {
            uint32_t p = pairs[e];
            int pos = atomicAdd(&cur[p >> 16], 1);
            stage[pos - e0] = (int)(p & 0xFFFF);
        }
        __syncthreads();
        for (int i = t; i < ecnt; i += 256) csr[e0 + i] = stage[i];  // coalesced
    } else {  // overflow fallback
        for (int e = e0 + t; e < e0 + ecnt; e += 256) {
            uint32_t p = pairs[e];
            int pos = atomicAdd(&cur[p >> 16], 1);
            csr[pos] = (int)(p & 0xFFFF);
        }
    }
}

// ---------- W split+transpose: W[K][N] fp32 -> Wt_hi/Wt_lo [N][K] bf16 ----------
template <int K, int NN>
__global__ __launch_bounds__(256) void k_wsplit(const float* __restrict__ W,
                                                uint16_t* __restrict__ Wth,
                                                uint16_t* __restrict__ Wtl) {
    int idx = blockIdx.x * 256 + threadIdx.x;
    if (idx >= K * NN) return;
    int k = idx / NN, n = idx % NN;
    float f = W[idx];
    uint16_t h = f2bf(f);
    uint16_t l = f2bf(f - bflo((uint32_t)h));
    Wth[n * K + k] = h;
    Wtl[n * K + k] = l;
}

// ---------- split-bf16 MFMA GEMM: Z = bf16( (X @ W) * dinv[row] ) ----------
// X [M][K] fp32; W given pre-split/transposed as Wt_hi/lo [NN][K] bf16.
// Each product term x*w = (xh+xl)(wh+wl) ~ xh*wh + xh*wl + xl*wh (3 MFMAs, fp32 acc).
// LDS tiles XOR-swizzled at 16B granularity: slot ^= (row&7)  (guide G4/T2).
template <int K, int NN>
__global__ __launch_bounds__(256) void k_gemm_mfma(const float* __restrict__ X,
                                                   const uint16_t* __restrict__ Wth,
                                                   const uint16_t* __restrict__ Wtl,
                                                   const float* __restrict__ dinv,
                                                   uint16_t* __restrict__ Z) {
    constexpr int BM = 64, BK = 64;
    constexpr int NW = NN / 64;  // 16-col n-tiles per wave (128->2, 64->1)
    __shared__ uint16_t Ah[BM * BK], Al[BM * BK], Wh[NN * BK], Wl[NN * BK];
    const int t = threadIdx.x;
    const int wave = t >> 6, lane = t & 63;
    const int bm = blockIdx.x * BM;
    const int r16 = lane & 15, kg = lane >> 4;
    const int n0 = wave * (NW * 16);
    f4x acc[4][NW] = {};

    for (int k0 = 0; k0 < K; k0 += BK) {
        {   // stage A: 64 rows x 64 k fp32 -> hi/lo bf16 (swizzled)
            int row = t >> 2, kq = (t & 3) * 16;
            const float* xp = X + (size_t)(bm + row) * K + k0 + kq;
            bool ok = (bm + row) < NNODES;
            float v[16];
#pragma unroll
            for (int u = 0; u < 4; ++u) {
                float4 f = ok ? *reinterpret_cast<const float4*>(xp + u * 4)
                              : make_float4(0.f, 0.f, 0.f, 0.f);
                v[u * 4 + 0] = f.x; v[u * 4 + 1] = f.y;
                v[u * 4 + 2] = f.z; v[u * 4 + 3] = f.w;
            }
            uint16_t hh[16], ll[16];
#pragma unroll
            for (int u = 0; u < 16; ++u) {
                uint16_t h = f2bf(v[u]);
                hh[u] = h;
                ll[u] = f2bf(v[u] - bflo((uint32_t)h));
            }
#pragma unroll
            for (int j = 0; j < 2; ++j) {
                int s = (t & 3) * 2 + j;
                int idx = (row * 8 + (s ^ (row & 7))) * 8;
                const uint16_t* hp = hh + j * 8;
                const uint16_t* lp = ll + j * 8;
                uint4 ph, pl;
                ph.x = hp[0] | ((uint32_t)hp[1] << 16);
                ph.y = hp[2] | ((uint32_t)hp[3] << 16);
                ph.z = hp[4] | ((uint32_t)hp[5] << 16);
                ph.w = hp[6] | ((uint32_t)hp[7] << 16);
                pl.x = lp[0] | ((uint32_t)lp[1] << 16);
                pl.y = lp[2] | ((uint32_t)lp[3] << 16);
                pl.z = lp[4] | ((uint32_t)lp[5] << 16);
                pl.w = lp[6] | ((uint32_t)lp[7] << 16);
                *reinterpret_cast<uint4*>(&Ah[idx]) = ph;
                *reinterpret_cast<uint4*>(&Al[idx]) = pl;
            }
        }
        {   // stage W: [NN][64] bf16 hi/lo from pre-transposed global (swizzled)
            constexpr int TPR = 256 / NN;  // threads per n-row
            constexpr int SPT = 8 / TPR;   // 16B slots per thread
            int n = t / TPR, q = t % TPR;
#pragma unroll
            for (int j = 0; j < SPT; ++j) {
                int s = q * SPT + j;
                uint4 vh = *reinterpret_cast<const uint4*>(&Wth[(size_t)n * K + k0 + s * 8]);
                uint4 vl = *reinterpret_cast<const uint4*>(&Wtl[(size_t)n * K + k0 + s * 8]);
                int idx = (n * 8 + (s ^ (n & 7))) * 8;
                *reinterpret_cast<uint4*>(&Wh[idx]) = vh;
                *reinterpret_cast<uint4*>(&Wl[idx]) = vl;
            }
        }
        __syncthreads();
#pragma unroll
        for (int ks = 0; ks < 2; ++ks) {  // two 32-deep MFMA k-steps per K-tile
            int kslot = ks * 4 + kg;
            b8 a_h[4], a_l[4];
#pragma unroll
            for (int mt = 0; mt < 4; ++mt) {
                int row = mt * 16 + r16;
                int idx = (row * 8 + (kslot ^ (row & 7))) * 8;
                a_h[mt] = *reinterpret_cast<const b8*>(&Ah[idx]);
                a_l[mt] = *reinterpret_cast<const b8*>(&Al[idx]);
            }
            b8 b_h[NW], b_l[NW];
#pragma unroll
            for (int nt = 0; nt < NW; ++nt) {
                int n = n0 + nt * 16 + r16;
                int idx = (n * 8 + (kslot ^ (n & 7))) * 8;
                b_h[nt] = *reinterpret_cast<const b8*>(&Wh[idx]);
                b_l[nt] = *reinterpret_cast<const b8*>(&Wl[idx]);
            }
#pragma unroll
            for (int mt = 0; mt < 4; ++mt)
#pragma unroll
                for (int nt = 0; nt < NW; ++nt) {
                    acc[mt][nt] = __builtin_amdgcn_mfma_f32_16x16x32_bf16(
                        a_h[mt], b_h[nt], acc[mt][nt], 0, 0, 0);
                    acc[mt][nt] = __builtin_amdgcn_mfma_f32_16x16x32_bf16(
                        a_h[mt], b_l[nt], acc[mt][nt], 0, 0, 0);
                    acc[mt][nt] = __builtin_amdgcn_mfma_f32_16x16x32_bf16(
                        a_l[mt], b_h[nt], acc[mt][nt], 0, 0, 0);
                }
        }
        __syncthreads();
    }
    // epilogue: C/D frag row=(lane>>4)*4+i, col=lane&15 [m89-verified]
#pragma unroll
    for (int mt = 0; mt < 4; ++mt) {
#pragma unroll
        for (int i = 0; i < 4; ++i) {
            int m = bm + mt * 16 + kg * 4 + i;
            if (m < NNODES) {
                float di = dinv[m];
#pragma unroll
                for (int nt = 0; nt < NW; ++nt) {
                    int n = n0 + nt * 16 + r16;
                    Z[(size_t)m * NN + n] = f2bf(acc[mt][nt][i] * di);
                }
            }
        }
    }
}

// ---------- aggregation: one wave per node, bf16 gather, fp32 accumulate ----------
template <int D>
__global__ __launch_bounds__(256) void k_agg_bf(const uint16_t* __restrict__ zs,
                                                const int* __restrict__ csr,
                                                const int* __restrict__ off,
                                                const float* __restrict__ dinv,
                                                const float* __restrict__ bias,
                                                float* __restrict__ out) {
    int wid = (blockIdx.x * 256 + threadIdx.x) >> 6;
    int lane = threadIdx.x & 63;
    if (wid >= NNODES) return;
    int start = off[wid];
    int c = off[wid + 1] - start;
    float di = dinv[wid];
    if constexpr (D == 128) {
        const uint32_t* Z = reinterpret_cast<const uint32_t*>(zs);  // 2 bf16 per u32
        uint32_t us = Z[(size_t)wid * 64 + lane];
        float ax = bflo(us), ay = bfhi(us);
        float bx = 0, by = 0, cx = 0, cy = 0, dx = 0, dy = 0;
        int j = 0;
        for (; j + 3 < c; j += 4) {
            int s0 = csr[start + j], s1 = csr[start + j + 1];
            int s2 = csr[start + j + 2], s3 = csr[start + j + 3];
            uint32_t u0 = Z[(size_t)s0 * 64 + lane];
            uint32_t u1 = Z[(size_t)s1 * 64 + lane];
            uint32_t u2 = Z[(size_t)s2 * 64 + lane];
            uint32_t u3 = Z[(size_t)s3 * 64 + lane];
            ax += bflo(u0); ay += bfhi(u0);
            bx += bflo(u1); by += bfhi(u1);
            cx += bflo(u2); cy += bfhi(u2);
            dx += bflo(u3); dy += bfhi(u3);
        }
        for (; j < c; ++j) {
            uint32_t u = Z[(size_t)csr[start + j] * 64 + lane];
            ax += bflo(u); ay += bfhi(u);
        }
        float sx = (ax + bx) + (cx + dx);
        float sy = (ay + by) + (cy + dy);
        float2 bv = *reinterpret_cast<const float2*>(bias + lane * 2);
        float2 o;
        o.x = fmaxf(fmaf(sx, di, bv.x), 0.f);
        o.y = fmaxf(fmaf(sy, di, bv.y), 0.f);
        *reinterpret_cast<float2*>(out + (size_t)wid * 128 + lane * 2) = o;
    } else {  // D == 64, one bf16 per lane
        float a = __uint_as_float(((uint32_t)zs[(size_t)wid * 64 + lane]) << 16);
        float b = 0, cc = 0, d = 0;
        int j = 0;
        for (; j + 3 < c; j += 4) {
            int s0 = csr[start + j], s1 = csr[start + j + 1];
            int s2 = csr[start + j + 2], s3 = csr[start + j + 3];
            a += __uint_as_float(((uint32_t)zs[(size_t)s0 * 64 + lane]) << 16);
            b += __uint_as_float(((uint32_t)zs[(size_t)s1 * 64 + lane]) << 16);
            cc += __uint_as_float(((uint32_t)zs[(size_t)s2 * 64 + lane]) << 16);
            d += __uint_as_float(((uint32_t)zs[(size_t)s3 * 64 + lane]) << 16);
        }
        for (; j < c; ++j)
            a += __uint_as_float(((uint32_t)zs[(size_t)csr[start + j] * 64 + lane]) << 16);
        float s = (a + b) + (cc + d);
        float o = fmaxf(fmaf(s, di, bias[lane]), 0.f);
        out[(size_t)wid * 64 + lane] = o;
    }
}

// ---------------- launcher ----------------
extern "C" void kernel_launch(void* const* d_in, const int* in_sizes, int n_in,
                              void* d_out, int out_size, void* d_ws, size_t ws_size,
                              hipStream_t stream) {
    const float* x = (const float*)d_in[0];
    const int* ei = (const int*)d_in[1];  // [2, E] int32
    const float* W1 = (const float*)d_in[2];
    const float* b1 = (const float*)d_in[3];
    const float* W2 = (const float*)d_in[4];
    const float* b2 = (const float*)d_in[5];
    float* out = (float*)d_out;

    char* ws = (char*)d_ws;
    int* counts = (int*)(ws + 0);                // NCHUNK*NBKT ints
    int* bktstart = (int*)(ws + 101376);
    int* bktcnt = (int*)(ws + 102400);
    int* off = (int*)(ws + 103424);              // (N+1)*4
    float* dinv = (float*)(ws + 303616);         // N*4
    int* csr = (int*)(ws + 503808);              // E*4 -> ends 6,903,808
    uint16_t* zs1 = (uint16_t*)(ws + 6904832);   // N*128 bf16 -> ends 19,704,832
    uint16_t* wt1h = (uint16_t*)(ws + 19705856); // 256*128 bf16 = 64KB
    uint16_t* wt1l = (uint16_t*)(ws + 19771392);
    uint16_t* wt2h = (uint16_t*)(ws + 19836928); // 128*64 bf16 = 16KB
    uint16_t* wt2l = (uint16_t*)(ws + 19853312);
    float* h1 = (float*)(ws + 19870720);         // N*128 fp32 -> ends 45,470,720
    uint32_t* pairs = (uint32_t*)h1;             // alias: pairs dead before h1 live
    uint16_t* zs2 = zs1;                         // alias: zs1 dead after agg1

    const int* esrc = ei;
    const int* edst = ei + NEDGES;

    k_wsplit<DIN, DH1><<<(DIN * DH1 + 255) / 256, 256, 0, stream>>>(W1, wt1h, wt1l);
    k_wsplit<DH1, DH2><<<(DH1 * DH2 + 255) / 256, 256, 0, stream>>>(W2, wt2h, wt2l);

    k_chunkhist<<<NCHUNK, 256, 0, stream>>>(edst, counts);
    k_bktscan<<<1, 256, 0, stream>>>(counts, bktstart, bktcnt);
    k_pairscatter<<<NCHUNK, 256, 0, stream>>>(esrc, edst, counts, pairs);
    k_sortbucket<<<NBKT, 256, 0, stream>>>(pairs, bktstart, bktcnt, csr, off, dinv);

    int gm = (NNODES + 63) / 64;  // 782
    k_gemm_mfma<DIN, DH1><<<gm, 256, 0, stream>>>(x, wt1h, wt1l, dinv, zs1);
    k_agg_bf<DH1><<<NNODES / 4, 256, 0, stream>>>(zs1, csr, off, dinv, b1, h1);

    k_gemm_mfma<DH1, DH2><<<gm, 256, 0, stream>>>(h1, wt2h, wt2l, dinv, zs2);
    k_agg_bf<DH2><<<NNODES / 4, 256, 0, stream>>>(zs2, csr, off, dinv, b2, out);
}

// Round 15
// 310.507 us; speedup vs baseline: 1.7018x; 1.0204x over previous
//
#include <hip/hip_runtime.h>
#include <hip/hip_bf16.h>
#include <cstdint>
#include <cstddef>

#define NNODES 50000
#define NEDGES 1600000
#define DIN 256
#define DH1 128
#define DH2 64

#define NBKT 196        // ceil(50000/256) buckets of 256 dst nodes
#define NCHUNK 196      // one edge-chunk per block
#define CHUNKE 8164     // 196*8164 = 1,600,144 >= 1.6M
#define STAGE_CAP 10240 // bucket edges ~8192±90; cap with big margin

__device__ __forceinline__ float bflo(uint32_t u) { return __uint_as_float(u << 16); }
__device__ __forceinline__ float bfhi(uint32_t u) { return __uint_as_float(u & 0xffff0000u); }
__device__ __forceinline__ uint16_t f2bf(float f) {
    uint32_t u = __float_as_uint(f);
    u += 0x7fffu + ((u >> 16) & 1u);  // round-to-nearest-even
    return (uint16_t)(u >> 16);
}

using b8 = __attribute__((ext_vector_type(8))) short;   // 8 bf16 = 4 VGPRs (MFMA A/B frag)
using f4x = __attribute__((ext_vector_type(4))) float;  // MFMA C/D frag

// ---------- pre1: W split+transpose AND per-chunk bucket histogram ----------
__global__ __launch_bounds__(256) void k_pre1(const float* __restrict__ W1g,
                                              const float* __restrict__ W2g,
                                              uint16_t* __restrict__ wt1h,
                                              uint16_t* __restrict__ wt1l,
                                              uint16_t* __restrict__ wt2h,
                                              uint16_t* __restrict__ wt2l,
                                              const int* __restrict__ dst,
                                              int* __restrict__ counts) {
    __shared__ int hist[256];
    const int b = blockIdx.x, t = threadIdx.x;
    // weight split+transpose (W[K][N] fp32 -> hi/lo bf16 [N][K]); gid < 40960
    {
        int gid = b * 256 + t;
        if (gid < DIN * DH1) {
            int k = gid / DH1, n = gid % DH1;
            float f = W1g[gid];
            uint16_t h = f2bf(f);
            wt1h[n * DIN + k] = h;
            wt1l[n * DIN + k] = f2bf(f - bflo((uint32_t)h));
        } else if (gid < DIN * DH1 + DH1 * DH2) {
            int i2 = gid - DIN * DH1;
            int k = i2 / DH2, n = i2 % DH2;
            float f = W2g[i2];
            uint16_t h = f2bf(f);
            wt2h[n * DH1 + k] = h;
            wt2l[n * DH1 + k] = f2bf(f - bflo((uint32_t)h));
        }
    }
    // per-chunk bucket histogram (block b = chunk b)
    hist[t] = 0;
    __syncthreads();
    const int e0 = b * CHUNKE, e1 = min(NEDGES, e0 + CHUNKE);
    for (int e = e0 + t; e < e1; e += 256) atomicAdd(&hist[dst[e] >> 8], 1);
    __syncthreads();
    if (t < NBKT) counts[b * NBKT + t] = hist[t];
}

// ---------- pre2: coarse bucket scatter (block b = chunk b) ----------
// Each block redundantly recomputes the bucket scan from `counts` (L2-hot,
// 150 KB) to get its own cursor bases — removes the separate scan dispatch.
__global__ __launch_bounds__(256) void k_pre2(const int* __restrict__ src,
                                              const int* __restrict__ dst,
                                              const int* __restrict__ counts,
                                              uint32_t* __restrict__ pairs) {
    __shared__ int cur[256];
    const int b = blockIdx.x, t = threadIdx.x;
    int tot = 0, myprefix = 0;
    if (t < NBKT) {
        for (int c = 0; c < NCHUNK; ++c) {
            int v = counts[c * NBKT + t];
            tot += v;
            if (c < b) myprefix += v;
        }
    }
    cur[t] = tot;
    __syncthreads();
    for (int d = 1; d < 256; d <<= 1) {  // inclusive scan of bucket totals
        int add = (t >= d) ? cur[t - d] : 0;
        __syncthreads();
        cur[t] += add;
        __syncthreads();
    }
    int base = cur[t] - tot + myprefix;  // bktstart[t] + prefix of chunks < b
    __syncthreads();
    cur[t] = base;
    __syncthreads();
    const int e0 = b * CHUNKE, e1 = min(NEDGES, e0 + CHUNKE);
    for (int e = e0 + t; e < e1; e += 256) {
        int d = dst[e];
        int pos = atomicAdd(&cur[d >> 8], 1);
        pairs[pos] = ((uint32_t)(d & 255) << 16) | (uint32_t)src[e];
    }
}

// ---------- pre3: per-bucket LDS sort -> csr, off, dinv (block b = bucket b) ----------
__global__ __launch_bounds__(256) void k_pre3(const uint32_t* __restrict__ pairs,
                                              const int* __restrict__ counts,
                                              int* __restrict__ csr,
                                              int* __restrict__ off,
                                              float* __restrict__ dinv) {
    __shared__ int hist[256];
    __shared__ int cur[256];
    __shared__ int stage[STAGE_CAP];
    const int b = blockIdx.x, t = threadIdx.x;
    // redundant bucket scan (same as pre2) to get this bucket's start/count
    int tot = 0;
    if (t < NBKT)
        for (int c = 0; c < NCHUNK; ++c) tot += counts[c * NBKT + t];
    cur[t] = tot;
    __syncthreads();
    for (int d = 1; d < 256; d <<= 1) {
        int add = (t >= d) ? cur[t - d] : 0;
        __syncthreads();
        cur[t] += add;
        __syncthreads();
    }
    hist[t] = cur[t] - tot;  // bktstart[t]
    stage[t] = tot;          // bktcnt[t]
    __syncthreads();
    const int be0 = hist[b], ecnt = stage[b];
    __syncthreads();
    // fine histogram over low byte of dst within the bucket
    hist[t] = 0;
    __syncthreads();
    for (int e = be0 + t; e < be0 + ecnt; e += 256)
        atomicAdd(&hist[pairs[e] >> 16], 1);
    __syncthreads();
    int v = hist[t];
    cur[t] = v;
    __syncthreads();
    for (int d = 1; d < 256; d <<= 1) {
        int add = (t >= d) ? cur[t - d] : 0;
        __syncthreads();
        cur[t] += add;
        __syncthreads();
    }
    int excl = cur[t] - v;  // within-bucket exclusive offset for node (b<<8)+t
    int node = (b << 8) + t;
    if (node < NNODES) {
        off[node] = be0 + excl;
        dinv[node] = rsqrtf((float)(v + 1));  // +1 self-loop
    }
    if (b == 0 && t == 0) off[NNODES] = NEDGES;
    __syncthreads();
    cur[t] = be0 + excl;  // global cursor
    __syncthreads();
    if (ecnt <= STAGE_CAP) {
        for (int e = be0 + t; e < be0 + ecnt; e += 256) {
            uint32_t p = pairs[e];
            int pos = atomicAdd(&cur[p >> 16], 1);
            stage[pos - be0] = (int)(p & 0xFFFF);
        }
        __syncthreads();
        for (int i = t; i < ecnt; i += 256) csr[be0 + i] = stage[i];  // coalesced
    } else {  // overflow fallback
        for (int e = be0 + t; e < be0 + ecnt; e += 256) {
            uint32_t p = pairs[e];
            int pos = atomicAdd(&cur[p >> 16], 1);
            csr[pos] = (int)(p & 0xFFFF);
        }
    }
}

// ---------- split-bf16 MFMA GEMM: Z = bf16( (X @ W) * dinv[row] ) ----------
// X [M][K] fp32; W pre-split/transposed Wt_hi/lo [NN][K] bf16.
// x*w = (xh+xl)(wh+wl) ~ xh*wh + xh*wl + xl*wh (3 MFMAs, fp32 acc).
// LDS tiles XOR-swizzled at 16B granularity: slot ^= (row&7)  (guide G4/T2).
template <int K, int NN>
__global__ __launch_bounds__(256) void k_gemm_mfma(const float* __restrict__ X,
                                                   const uint16_t* __restrict__ Wth,
                                                   const uint16_t* __restrict__ Wtl,
                                                   const float* __restrict__ dinv,
                                                   uint16_t* __restrict__ Z) {
    constexpr int BM = 64, BK = 64;
    constexpr int NW = NN / 64;  // 16-col n-tiles per wave (128->2, 64->1)
    __shared__ uint16_t Ah[BM * BK], Al[BM * BK], Wh[NN * BK], Wl[NN * BK];
    const int t = threadIdx.x;
    const int wave = t >> 6, lane = t & 63;
    const int bm = blockIdx.x * BM;
    const int r16 = lane & 15, kg = lane >> 4;
    const int n0 = wave * (NW * 16);
    f4x acc[4][NW] = {};

    for (int k0 = 0; k0 < K; k0 += BK) {
        {   // stage A: 64 rows x 64 k fp32 -> hi/lo bf16 (swizzled)
            int row = t >> 2, kq = (t & 3) * 16;
            const float* xp = X + (size_t)(bm + row) * K + k0 + kq;
            bool ok = (bm + row) < NNODES;
            float v[16];
#pragma unroll
            for (int u = 0; u < 4; ++u) {
                float4 f = ok ? *reinterpret_cast<const float4*>(xp + u * 4)
                              : make_float4(0.f, 0.f, 0.f, 0.f);
                v[u * 4 + 0] = f.x; v[u * 4 + 1] = f.y;
                v[u * 4 + 2] = f.z; v[u * 4 + 3] = f.w;
            }
            uint16_t hh[16], ll[16];
#pragma unroll
            for (int u = 0; u < 16; ++u) {
                uint16_t h = f2bf(v[u]);
                hh[u] = h;
                ll[u] = f2bf(v[u] - bflo((uint32_t)h));
            }
#pragma unroll
            for (int j = 0; j < 2; ++j) {
                int s = (t & 3) * 2 + j;
                int idx = (row * 8 + (s ^ (row & 7))) * 8;
                const uint16_t* hp = hh + j * 8;
                const uint16_t* lp = ll + j * 8;
                uint4 ph, pl;
                ph.x = hp[0] | ((uint32_t)hp[1] << 16);
                ph.y = hp[2] | ((uint32_t)hp[3] << 16);
                ph.z = hp[4] | ((uint32_t)hp[5] << 16);
                ph.w = hp[6] | ((uint32_t)hp[7] << 16);
                pl.x = lp[0] | ((uint32_t)lp[1] << 16);
                pl.y = lp[2] | ((uint32_t)lp[3] << 16);
                pl.z = lp[4] | ((uint32_t)lp[5] << 16);
                pl.w = lp[6] | ((uint32_t)lp[7] << 16);
                *reinterpret_cast<uint4*>(&Ah[idx]) = ph;
                *reinterpret_cast<uint4*>(&Al[idx]) = pl;
            }
        }
        {   // stage W: [NN][64] bf16 hi/lo from pre-transposed global (swizzled)
            constexpr int TPR = 256 / NN;  // threads per n-row
            constexpr int SPT = 8 / TPR;   // 16B slots per thread
            int n = t / TPR, q = t % TPR;
#pragma unroll
            for (int j = 0; j < SPT; ++j) {
                int s = q * SPT + j;
                uint4 vh = *reinterpret_cast<const uint4*>(&Wth[(size_t)n * K + k0 + s * 8]);
                uint4 vl = *reinterpret_cast<const uint4*>(&Wtl[(size_t)n * K + k0 + s * 8]);
                int idx = (n * 8 + (s ^ (n & 7))) * 8;
                *reinterpret_cast<uint4*>(&Wh[idx]) = vh;
                *reinterpret_cast<uint4*>(&Wl[idx]) = vl;
            }
        }
        __syncthreads();
#pragma unroll
        for (int ks = 0; ks < 2; ++ks) {  // two 32-deep MFMA k-steps per K-tile
            int kslot = ks * 4 + kg;
            b8 a_h[4], a_l[4];
#pragma unroll
            for (int mt = 0; mt < 4; ++mt) {
                int row = mt * 16 + r16;
                int idx = (row * 8 + (kslot ^ (row & 7))) * 8;
                a_h[mt] = *reinterpret_cast<const b8*>(&Ah[idx]);
                a_l[mt] = *reinterpret_cast<const b8*>(&Al[idx]);
            }
            b8 b_h[NW], b_l[NW];
#pragma unroll
            for (int nt = 0; nt < NW; ++nt) {
                int n = n0 + nt * 16 + r16;
                int idx = (n * 8 + (kslot ^ (n & 7))) * 8;
                b_h[nt] = *reinterpret_cast<const b8*>(&Wh[idx]);
                b_l[nt] = *reinterpret_cast<const b8*>(&Wl[idx]);
            }
#pragma unroll
            for (int mt = 0; mt < 4; ++mt)
#pragma unroll
                for (int nt = 0; nt < NW; ++nt) {
                    acc[mt][nt] = __builtin_amdgcn_mfma_f32_16x16x32_bf16(
                        a_h[mt], b_h[nt], acc[mt][nt], 0, 0, 0);
                    acc[mt][nt] = __builtin_amdgcn_mfma_f32_16x16x32_bf16(
                        a_h[mt], b_l[nt], acc[mt][nt], 0, 0, 0);
                    acc[mt][nt] = __builtin_amdgcn_mfma_f32_16x16x32_bf16(
                        a_l[mt], b_h[nt], acc[mt][nt], 0, 0, 0);
                }
        }
        __syncthreads();
    }
    // epilogue: C/D frag row=(lane>>4)*4+i, col=lane&15 [m89-verified]
#pragma unroll
    for (int mt = 0; mt < 4; ++mt) {
#pragma unroll
        for (int i = 0; i < 4; ++i) {
            int m = bm + mt * 16 + kg * 4 + i;
            if (m < NNODES) {
                float di = dinv[m];
#pragma unroll
                for (int nt = 0; nt < NW; ++nt) {
                    int n = n0 + nt * 16 + r16;
                    Z[(size_t)m * NN + n] = f2bf(acc[mt][nt][i] * di);
                }
            }
        }
    }
}

// ---------- aggregation: one wave per node, bf16 gather, fp32 accumulate ----------
template <int D>
__global__ __launch_bounds__(256) void k_agg_bf(const uint16_t* __restrict__ zs,
                                                const int* __restrict__ csr,
                                                const int* __restrict__ off,
                                                const float* __restrict__ dinv,
                                                const float* __restrict__ bias,
                                                float* __restrict__ out) {
    int wid = (blockIdx.x * 256 + threadIdx.x) >> 6;
    int lane = threadIdx.x & 63;
    if (wid >= NNODES) return;
    int start = off[wid];
    int c = off[wid + 1] - start;
    float di = dinv[wid];
    if constexpr (D == 128) {
        const uint32_t* Z = reinterpret_cast<const uint32_t*>(zs);  // 2 bf16 per u32
        uint32_t us = Z[(size_t)wid * 64 + lane];
        float ax = bflo(us), ay = bfhi(us);
        float bx = 0, by = 0, cx = 0, cy = 0, dx = 0, dy = 0;
        int j = 0;
        for (; j + 3 < c; j += 4) {
            int s0 = csr[start + j], s1 = csr[start + j + 1];
            int s2 = csr[start + j + 2], s3 = csr[start + j + 3];
            uint32_t u0 = Z[(size_t)s0 * 64 + lane];
            uint32_t u1 = Z[(size_t)s1 * 64 + lane];
            uint32_t u2 = Z[(size_t)s2 * 64 + lane];
            uint32_t u3 = Z[(size_t)s3 * 64 + lane];
            ax += bflo(u0); ay += bfhi(u0);
            bx += bflo(u1); by += bfhi(u1);
            cx += bflo(u2); cy += bfhi(u2);
            dx += bflo(u3); dy += bfhi(u3);
        }
        for (; j < c; ++j) {
            uint32_t u = Z[(size_t)csr[start + j] * 64 + lane];
            ax += bflo(u); ay += bfhi(u);
        }
        float sx = (ax + bx) + (cx + dx);
        float sy = (ay + by) + (cy + dy);
        float2 bv = *reinterpret_cast<const float2*>(bias + lane * 2);
        float2 o;
        o.x = fmaxf(fmaf(sx, di, bv.x), 0.f);
        o.y = fmaxf(fmaf(sy, di, bv.y), 0.f);
        *reinterpret_cast<float2*>(out + (size_t)wid * 128 + lane * 2) = o;
    } else {  // D == 64, one bf16 per lane
        float a = __uint_as_float(((uint32_t)zs[(size_t)wid * 64 + lane]) << 16);
        float b = 0, cc = 0, d = 0;
        int j = 0;
        for (; j + 3 < c; j += 4) {
            int s0 = csr[start + j], s1 = csr[start + j + 1];
            int s2 = csr[start + j + 2], s3 = csr[start + j + 3];
            a += __uint_as_float(((uint32_t)zs[(size_t)s0 * 64 + lane]) << 16);
            b += __uint_as_float(((uint32_t)zs[(size_t)s1 * 64 + lane]) << 16);
            cc += __uint_as_float(((uint32_t)zs[(size_t)s2 * 64 + lane]) << 16);
            d += __uint_as_float(((uint32_t)zs[(size_t)s3 * 64 + lane]) << 16);
        }
        for (; j < c; ++j)
            a += __uint_as_float(((uint32_t)zs[(size_t)csr[start + j] * 64 + lane]) << 16);
        float s = (a + b) + (cc + d);
        float o = fmaxf(fmaf(s, di, bias[lane]), 0.f);
        out[(size_t)wid * 64 + lane] = o;
    }
}

// ---------------- launcher ----------------
extern "C" void kernel_launch(void* const* d_in, const int* in_sizes, int n_in,
                              void* d_out, int out_size, void* d_ws, size_t ws_size,
                              hipStream_t stream) {
    const float* x = (const float*)d_in[0];
    const int* ei = (const int*)d_in[1];  // [2, E] int32
    const float* W1 = (const float*)d_in[2];
    const float* b1 = (const float*)d_in[3];
    const float* W2 = (const float*)d_in[4];
    const float* b2 = (const float*)d_in[5];
    float* out = (float*)d_out;

    char* ws = (char*)d_ws;
    int* counts = (int*)(ws + 0);                 // 196*196*4 = 153,664 B
    int* off = (int*)(ws + 156672);               // (N+1)*4 -> ends 356,676
    float* dinv = (float*)(ws + 357376);          // N*4 -> ends 557,376
    int* csr = (int*)(ws + 557568);               // E*4 -> ends 6,957,568
    uint16_t* zs1 = (uint16_t*)(ws + 6957568);    // N*128 bf16 -> ends 19,757,568
    uint16_t* wt1h = (uint16_t*)(ws + 19757568);  // 64 KB
    uint16_t* wt1l = (uint16_t*)(ws + 19823104);  // 64 KB
    uint16_t* wt2h = (uint16_t*)(ws + 19888640);  // 16 KB
    uint16_t* wt2l = (uint16_t*)(ws + 19905024);  // 16 KB
    float* h1 = (float*)(ws + 19921408);          // N*128 fp32 -> ends 45,521,408
    uint32_t* pairs = (uint32_t*)h1;              // alias: pairs dead before h1 live
    uint16_t* zs2 = zs1;                          // alias: zs1 dead after agg1

    const int* esrc = ei;
    const int* edst = ei + NEDGES;

    k_pre1<<<NCHUNK, 256, 0, stream>>>(W1, W2, wt1h, wt1l, wt2h, wt2l, edst, counts);
    k_pre2<<<NCHUNK, 256, 0, stream>>>(esrc, edst, counts, pairs);
    k_pre3<<<NBKT, 256, 0, stream>>>(pairs, counts, csr, off, dinv);

    int gm = (NNODES + 63) / 64;  // 782
    k_gemm_mfma<DIN, DH1><<<gm, 256, 0, stream>>>(x, wt1h, wt1l, dinv, zs1);
    k_agg_bf<DH1><<<NNODES / 4, 256, 0, stream>>>(zs1, csr, off, dinv, b1, h1);

    k_gemm_mfma<DH1, DH2><<<gm, 256, 0, stream>>>(h1, wt2h, wt2l, dinv, zs2);
    k_agg_bf<DH2><<<NNODES / 4, 256, 0, stream>>>(zs2, csr, off, dinv, b2, out);
}